// Round 1
// baseline (637.801 us; speedup 1.0000x reference)
//
#include <hip/hip_runtime.h>

#define NF 4097
#define N2 4096
#define LOGN2 12
#define KSEL 819          // int(4097 * 0.2)
#define BATCH 64
#define CH 32
#define LEN 8192
#define TWPAD 2112        // 2048 + 2048/32 padded twiddle table

__device__ __forceinline__ int SW(int i) { return i ^ ((i >> 6) & 63); }
__device__ __forceinline__ unsigned sukey(float f) {
  unsigned u = __float_as_uint(f);
  return (u & 0x80000000u) ? ~u : (u | 0x80000000u);
}

// ---- K0: diag extract, entropy zero, fp64-accurate twiddle tables ----
__global__ __launch_bounds__(256) void prep_kernel(
    const float* __restrict__ w1, float* __restrict__ diag,
    float* __restrict__ gtw, float* __restrict__ guntw, float* __restrict__ ent)
{
  int i = blockIdx.x * 256 + threadIdx.x;
  if (i < NF) {
    diag[i] = w1[(size_t)i * (NF + 1)];
  } else if (i < 2 * NF) {
    int f = i - NF;
    diag[i] = w1[(size_t)NF * NF + (size_t)f * (NF + 1)];
  } else if (i < 2 * NF + BATCH) {
    ent[i - 2 * NF] = 0.0f;
  } else if (i < 2 * NF + BATCH + 2048) {
    int m = i - (2 * NF + BATCH);
    double ang = -6.283185307179586 * (double)m / 4096.0;
    int p = m + (m >> 5);
    gtw[p] = (float)cos(ang);
    gtw[TWPAD + p] = (float)sin(ang);
  } else if (i < 2 * NF + BATCH + 2048 + NF) {
    int k = i - (2 * NF + BATCH + 2048);
    double ang = -6.283185307179586 * (double)k / 8192.0;
    guntw[k] = (float)cos(ang);
    guntw[NF + k] = (float)sin(ang);
  }
}

// ---- K1: [B][R][32] -> [B][32][R] tiled transpose ----
__global__ __launch_bounds__(256) void transpose_kernel(
    const float* __restrict__ src, float* __restrict__ dst, int R)
{
  __shared__ float tile[32][33];
  int tx = threadIdx.x & 31, ty = threadIdx.x >> 5;
  int r0 = blockIdx.x * 32;
  size_t b = blockIdx.y;
  const float* s = src + b * (size_t)R * 32;
  float* d = dst + b * (size_t)32 * R;
  #pragma unroll
  for (int i = 0; i < 4; i++) {
    int r = r0 + ty + 8 * i;
    if (r < R) tile[tx][ty + 8 * i] = s[(size_t)r * 32 + tx];
  }
  __syncthreads();
  #pragma unroll
  for (int i = 0; i < 4; i++) {
    int c = ty + 8 * i;
    int r = r0 + tx;
    if (r < R) d[(size_t)c * R + r] = tile[c][tx];
  }
}

// ---- K3: transpose back + x_var = x - x_inv ----
__global__ __launch_bounds__(256) void finalize_kernel(
    const float* __restrict__ xinv_t, const float* __restrict__ x,
    float* __restrict__ xvar, float* __restrict__ xinv)
{
  __shared__ float tile[32][33];
  int tx = threadIdx.x & 31, ty = threadIdx.x >> 5;
  int l0 = blockIdx.x * 32;
  size_t b = blockIdx.y;
  const float* s = xinv_t + b * (size_t)CH * LEN;
  #pragma unroll
  for (int i = 0; i < 4; i++) {
    int c = ty + 8 * i;
    tile[tx][c] = s[(size_t)c * LEN + l0 + tx];
  }
  __syncthreads();
  #pragma unroll
  for (int i = 0; i < 4; i++) {
    int l = l0 + ty + 8 * i;
    size_t idx = (b * LEN + l) * CH + tx;
    float v = tile[ty + 8 * i][tx];
    xinv[idx] = v;
    xvar[idx] = x[idx] - v;
  }
}

// ---- K2: per-(b,c): rfft -> logits -> gumbel softmax -> top-k -> irfft ----
__global__ __launch_bounds__(256) void spectral_kernel(
    float* __restrict__ xt, const float* __restrict__ ut,
    const float* __restrict__ diag, const float* __restrict__ b1g,
    const float* __restrict__ gtw, const float* __restrict__ guntw,
    float* __restrict__ ent)
{
  __shared__ float sre[NF + 3];
  __shared__ float sim[NF + 3];
  __shared__ float yv[2 * TWPAD];   // twiddle LUT during FFTs; y_soft during selection
  __shared__ float redbuf[8];
  __shared__ unsigned hist[256];
  __shared__ unsigned ubc[4];
  __shared__ float fbc[2];
  __shared__ int tielist[64];

  const int tid = threadIdx.x;
  const int bc = blockIdx.x;
  float* xrow = xt + (size_t)bc * LEN;
  const float* urow = ut + (size_t)bc * NF;
  const float* twc = yv;
  const float* tws = yv + TWPAD;

  // load twiddle LUT + data (coalesced global, swizzled bitrev LDS scatter)
  for (int i = tid; i < 2 * TWPAD; i += 256) yv[i] = gtw[i];
  #pragma unroll
  for (int i = 0; i < 16; i++) {
    int n = tid + 256 * i;
    float2 v = ((const float2*)xrow)[n];
    int p = SW(__brev((unsigned)n) >> 20);
    sre[p] = v.x; sim[p] = v.y;
  }
  __syncthreads();

  // forward 4096-pt DIT FFT of z[n] = x[2n] + i x[2n+1]
  for (int s = 1; s <= LOGN2; s++) {
    const int half = 1 << (s - 1);
    const int shift = LOGN2 - s;
    for (int t = tid; t < N2 / 2; t += 256) {
      const int j = t & (half - 1);
      const int i0 = ((t >> (s - 1)) << s) + j;
      const int m = j << shift;
      const int mp = m + (m >> 5);
      const float cw = twc[mp], sw = tws[mp];
      const int a0 = SW(i0), a1 = SW(i0 + half);
      const float vr = sre[a1], vi = sim[a1];
      const float ur = sre[a0], ui = sim[a0];
      const float tr = vr * cw - vi * sw;
      const float ti = vr * sw + vi * cw;
      sre[a0] = ur + tr; sim[a0] = ui + ti;
      sre[a1] = ur - tr; sim[a1] = ui - ti;
    }
    __syncthreads();
  }

  // untangle: Z[0..4095] -> X[0..4096] (rfft of 8192 real samples)
  {
    float txr[17], txi[17];
    #pragma unroll
    for (int i = 0; i < 17; i++) {
      const int k = tid + 256 * i;
      if (k <= N2) {
        const int kk = k & (N2 - 1), km = (N2 - k) & (N2 - 1);
        const float a = sre[SW(kk)], b = sim[SW(kk)];
        const float c = sre[SW(km)], d = sim[SW(km)];
        const float xer = 0.5f * (a + c), xei = 0.5f * (b - d);
        const float xor_ = 0.5f * (b + d), xoi = 0.5f * (c - a);
        const float cw = guntw[k], sw = guntw[NF + k];  // e^{-2pi i k/8192}
        txr[i] = xer + xor_ * cw - xoi * sw;
        txi[i] = xei + xor_ * sw + xoi * cw;
      }
    }
    __syncthreads();
    #pragma unroll
    for (int i = 0; i < 17; i++) {
      const int k = tid + 256 * i;
      if (k <= N2) { sre[SW(k)] = txr[i]; sim[SW(k)] = txi[i]; }
    }
    __syncthreads();
  }

  // logits + gumbel -> z = (logit + g)/TAU
  float zloc[17], yloc[17];
  float lmax = -3.0e38f;
  #pragma unroll
  for (int i = 0; i < 17; i++) {
    const int k = tid + 256 * i;
    if (k <= N2) {
      const float re = sre[SW(k)], im = sim[SW(k)];
      const float d0 = diag[k], d1 = diag[NF + k];
      const float o_r = fmaxf(re * d0 - im * d1 + b1g[k], 0.0f);
      const float o_i = fmaxf(im * d0 + re * d1 + b1g[NF + k], 0.0f);
      const float logit = sqrtf(o_r * o_r + o_i * o_i);
      const float u = urow[k];
      const float g = -logf(-logf(u + 1e-10f) + 1e-10f);
      const float z = (logit + g) * 2.0f;   // 1/TAU
      zloc[i] = z;
      lmax = fmaxf(lmax, z);
    }
  }
  #pragma unroll
  for (int off = 32; off; off >>= 1) lmax = fmaxf(lmax, __shfl_xor(lmax, off, 64));
  if ((tid & 63) == 0) redbuf[tid >> 6] = lmax;
  __syncthreads();
  if (tid == 0) fbc[0] = fmaxf(fmaxf(redbuf[0], redbuf[1]), fmaxf(redbuf[2], redbuf[3]));
  __syncthreads();
  const float mx = fbc[0];

  float s1 = 0.0f, s2 = 0.0f;
  #pragma unroll
  for (int i = 0; i < 17; i++) {
    const int k = tid + 256 * i;
    if (k <= N2) {
      const float t = zloc[i] - mx;
      const float e = expf(t);
      s1 += e; s2 += t * e;
      yloc[i] = e;
    }
  }
  #pragma unroll
  for (int off = 32; off; off >>= 1) { s1 += __shfl_xor(s1, off, 64); s2 += __shfl_xor(s2, off, 64); }
  if ((tid & 63) == 0) { redbuf[tid >> 6] = s1; redbuf[4 + (tid >> 6)] = s2; }
  __syncthreads();
  if (tid == 0) {
    const float S1a = redbuf[0] + redbuf[1] + redbuf[2] + redbuf[3];
    const float S2a = redbuf[4] + redbuf[5] + redbuf[6] + redbuf[7];
    fbc[1] = S1a;
    atomicAdd(&ent[bc >> 5], (logf(S1a) - S2a / S1a) * (1.0f / CH));
  }
  __syncthreads();
  const float S1 = fbc[1];
  #pragma unroll
  for (int i = 0; i < 17; i++) {
    const int k = tid + 256 * i;
    if (k <= N2) { const float y = yloc[i] / S1; yloc[i] = y; yv[k] = y; }
  }

  // radix-select the 819th largest y_soft
  unsigned prefix = 0u, rank = KSEL;
  for (int p = 24; p >= 0; p -= 8) {
    hist[tid] = 0u;
    __syncthreads();
    #pragma unroll
    for (int i = 0; i < 17; i++) {
      const int k = tid + 256 * i;
      if (k <= N2) {
        const unsigned su = sukey(yloc[i]);
        if (((su >> p) >> 8) == ((prefix >> p) >> 8))
          atomicAdd(&hist[(su >> p) & 255u], 1u);
      }
    }
    __syncthreads();
    if (tid == 0) {
      unsigned c = 0; int bsel = 0;
      for (int bn = 255; bn >= 0; bn--) {
        const unsigned nc = c + hist[bn];
        if (nc >= rank) { bsel = bn; break; }
        c = nc;
      }
      ubc[0] = prefix | ((unsigned)bsel << p);
      ubc[1] = rank - c;
    }
    __syncthreads();
    prefix = ubc[0]; rank = ubc[1];
  }
  const unsigned T = prefix;
  const unsigned need_eq = rank;

  // stable-argsort tie handling: keep lowest-index equals
  if (tid == 0) ubc[2] = 0u;
  __syncthreads();
  #pragma unroll
  for (int i = 0; i < 17; i++) {
    const int k = tid + 256 * i;
    if (k <= N2 && sukey(yloc[i]) == T) {
      const unsigned pos = atomicAdd(&ubc[2], 1u);
      if (pos < 64u) tielist[pos] = k;
    }
  }
  __syncthreads();
  if (tid == 0) {
    int n = (int)ubc[2]; if (n > 64) n = 64;
    for (int a = 1; a < n; a++) {
      const int key = tielist[a]; int j = a - 1;
      while (j >= 0 && tielist[j] > key) { tielist[j + 1] = tielist[j]; j--; }
      tielist[j + 1] = key;
    }
    for (int j = (int)need_eq; j < n; j++) yv[tielist[j]] = -1.0f;
  }
  __syncthreads();

  // hard mask: zero non-selected bins
  #pragma unroll
  for (int i = 0; i < 17; i++) {
    const int k = tid + 256 * i;
    if (k <= N2) {
      if (sukey(yv[k]) < T) { sre[SW(k)] = 0.0f; sim[SW(k)] = 0.0f; }
    }
  }
  __syncthreads();

  // reload twiddle LUT + inverse untangle X -> Z
  for (int i = tid; i < 2 * TWPAD; i += 256) yv[i] = gtw[i];
  {
    float tzr[16], tzi[16];
    #pragma unroll
    for (int i = 0; i < 16; i++) {
      const int k = tid + 256 * i;
      const int km = N2 - k;
      const float a = sre[SW(k)], b = sim[SW(k)];
      const float c = sre[SW(km)], d = sim[SW(km)];
      const float xer = 0.5f * (a + c), xei = 0.5f * (b - d);
      const float tr = 0.5f * (a - c), ti = 0.5f * (b + d);
      const float cw = guntw[k], sw = -guntw[NF + k];  // e^{+2pi i k/8192}
      const float xor_ = tr * cw - ti * sw, xoi = tr * sw + ti * cw;
      tzr[i] = xer - xoi;
      tzi[i] = xei + xor_;
    }
    __syncthreads();
    #pragma unroll
    for (int i = 0; i < 16; i++) {
      const int k = tid + 256 * i;
      sre[SW(k)] = tzr[i]; sim[SW(k)] = tzi[i];
    }
    __syncthreads();
  }

  // inverse 4096-pt DIF FFT (natural in -> bitrev out)
  for (int s = LOGN2; s >= 1; s--) {
    const int half = 1 << (s - 1);
    const int shift = LOGN2 - s;
    for (int t = tid; t < N2 / 2; t += 256) {
      const int j = t & (half - 1);
      const int i0 = ((t >> (s - 1)) << s) + j;
      const int m = j << shift;
      const int mp = m + (m >> 5);
      const float cw = twc[mp], sw = -tws[mp];
      const int a0 = SW(i0), a1 = SW(i0 + half);
      const float ur = sre[a0], ui = sim[a0];
      const float vr = sre[a1], vi = sim[a1];
      sre[a0] = ur + vr; sim[a0] = ui + vi;
      const float dr = ur - vr, di = ui - vi;
      sre[a1] = dr * cw - di * sw;
      sim[a1] = dr * sw + di * cw;
    }
    __syncthreads();
  }

  // write x_inv row (coalesced; swizzled bitrev LDS gather), scale 1/4096
  const float scale = 1.0f / N2;
  #pragma unroll
  for (int i = 0; i < 16; i++) {
    const int n = tid + 256 * i;
    const int p = SW(__brev((unsigned)n) >> 20);
    float2 v; v.x = sre[p] * scale; v.y = sim[p] * scale;
    ((float2*)xrow)[n] = v;
  }
}

extern "C" void kernel_launch(void* const* d_in, const int* in_sizes, int n_in,
                              void* d_out, int out_size, void* d_ws, size_t ws_size,
                              hipStream_t stream) {
  (void)in_sizes; (void)n_in; (void)out_size; (void)ws_size;
  const float* x  = (const float*)d_in[0];
  const float* w1 = (const float*)d_in[1];
  const float* b1 = (const float*)d_in[2];
  const float* un = (const float*)d_in[3];
  float* xvar = (float*)d_out;
  float* xinv = xvar + (size_t)BATCH * LEN * CH;
  float* ent  = xinv + (size_t)BATCH * LEN * CH;

  float* xt    = (float*)d_ws;                       // [B*C][LEN], reused as x_inv_t
  float* ut    = xt + (size_t)BATCH * CH * LEN;      // [B*C][NF]
  float* diag  = ut + (size_t)BATCH * CH * NF;       // [2*NF]
  float* gtw   = diag + 2 * NF;                      // [2*TWPAD]
  float* guntw = gtw + 2 * TWPAD;                    // [2*NF]

  prep_kernel<<<57, 256, 0, stream>>>(w1, diag, gtw, guntw, ent);
  transpose_kernel<<<dim3(LEN / 32, BATCH), 256, 0, stream>>>(x, xt, LEN);
  transpose_kernel<<<dim3((NF + 31) / 32, BATCH), 256, 0, stream>>>(un, ut, NF);
  spectral_kernel<<<BATCH * CH, 256, 0, stream>>>(xt, ut, diag, b1, gtw, guntw, ent);
  finalize_kernel<<<dim3(LEN / 32, BATCH), 256, 0, stream>>>(xt, x, xvar, xinv);
}

// Round 2
// 455.287 us; speedup vs baseline: 1.4009x; 1.4009x over previous
//
#include <hip/hip_runtime.h>

#define NF 4097
#define N2 4096
#define KSEL 819          // int(4097 * 0.2)
#define BATCH 64
#define CH 32
#define LEN 8192

#define POS(i) ((i) + ((i) >> 4))   // LDS anti-conflict pad: +1 word per 16

__device__ __forceinline__ unsigned sukey(float f) {
  unsigned u = __float_as_uint(f);
  return (u & 0x80000000u) ? ~u : (u | 0x80000000u);
}

// ---------------- 16-point DFT in registers (2 x radix-4) ----------------
template<bool INV>
__device__ __forceinline__ void dft16(float vr[16], float vi[16]) {
  const float K1 = 0.9238795325112867f;   // cos(pi/8)
  const float K3 = 0.3826834323650898f;   // sin(pi/8)
  const float K2 = 0.7071067811865476f;   // sqrt(2)/2
  // w16^t = (TWC[t], -TWS[t]) forward; conj for inverse
  const float TWC[10] = {1.f, K1, K2, K3, 0.f, -K3, -K2, -K1, -1.f, -K1};
  const float TWS[10] = {0.f, K3, K2, K1, 1.f,  K1,  K2,  K3,  0.f, -K3};
  float yr[16], yi[16];
  #pragma unroll
  for (int q0 = 0; q0 < 4; q0++) {
    const float ar = vr[q0],      ai = vi[q0];
    const float br = vr[4 + q0],  bi = vi[4 + q0];
    const float cr = vr[8 + q0],  ci = vi[8 + q0];
    const float dr = vr[12 + q0], di = vi[12 + q0];
    const float t0r = ar + cr, t0i = ai + ci;
    const float t1r = ar - cr, t1i = ai - ci;
    const float t2r = br + dr, t2i = bi + di;
    const float t3r = br - dr, t3i = bi - di;
    yr[q0*4+0] = t0r + t2r; yi[q0*4+0] = t0i + t2i;
    yr[q0*4+2] = t0r - t2r; yi[q0*4+2] = t0i - t2i;
    if (!INV) {
      yr[q0*4+1] = t1r + t3i; yi[q0*4+1] = t1i - t3r;
      yr[q0*4+3] = t1r - t3i; yi[q0*4+3] = t1i + t3r;
    } else {
      yr[q0*4+1] = t1r - t3i; yi[q0*4+1] = t1i + t3r;
      yr[q0*4+3] = t1r + t3i; yi[q0*4+3] = t1i - t3r;
    }
  }
  #pragma unroll
  for (int q0 = 1; q0 < 4; q0++) {
    #pragma unroll
    for (int p0 = 1; p0 < 4; p0++) {
      const int t = q0 * p0;
      const float c = TWC[t];
      const float s = INV ? TWS[t] : -TWS[t];
      const int idx = q0*4 + p0;
      const float rr = yr[idx]*c - yi[idx]*s;
      const float ii = yr[idx]*s + yi[idx]*c;
      yr[idx] = rr; yi[idx] = ii;
    }
  }
  #pragma unroll
  for (int p0 = 0; p0 < 4; p0++) {
    const float ar = yr[0*4+p0],  ai = yi[0*4+p0];
    const float br = yr[1*4+p0],  bi = yi[1*4+p0];
    const float cr = yr[2*4+p0],  ci = yi[2*4+p0];
    const float dr = yr[3*4+p0],  di = yi[3*4+p0];
    const float t0r = ar + cr, t0i = ai + ci;
    const float t1r = ar - cr, t1i = ai - ci;
    const float t2r = br + dr, t2i = bi + di;
    const float t3r = br - dr, t3i = bi - di;
    vr[0*4+p0] = t0r + t2r;  vi[0*4+p0] = t0i + t2i;
    vr[2*4+p0] = t0r - t2r;  vi[2*4+p0] = t0i - t2i;
    if (!INV) {
      vr[1*4+p0] = t1r + t3i; vi[1*4+p0] = t1i - t3r;
      vr[3*4+p0] = t1r - t3i; vi[3*4+p0] = t1i + t3r;
    } else {
      vr[1*4+p0] = t1r - t3i; vi[1*4+p0] = t1i + t3r;
      vr[3*4+p0] = t1r + t3i; vi[3*4+p0] = t1i - t3r;
    }
  }
}

// stage twiddle: v_p *= w^p via recurrence (w fp64-accurate from LUT)
template<bool INV>
__device__ __forceinline__ void stage_twiddle(float vr[16], float vi[16], float2 w) {
  const float wr = w.x, wi = INV ? -w.y : w.y;
  float cr = wr, ci = wi;
  #pragma unroll
  for (int p = 1; p < 16; p++) {
    const float nr = vr[p]*cr - vi[p]*ci;
    const float ni = vr[p]*ci + vi[p]*cr;
    vr[p] = nr; vi[p] = ni;
    const float ar = cr*wr - ci*wi;
    const float ai = cr*wi + ci*wr;
    cr = ar; ci = ai;
  }
}

// 4096-pt radix-16 DIF FFT. Data natural-order in LDS on entry AND exit
// (digit-reversal folded into the last stage's scatter). Caller must have
// barriered so LDS is visible. Leaves a barrier after the final scatter.
template<bool INV>
__device__ __forceinline__ void fft4096(float* sre, float* sim, int tid,
                                        const float2* __restrict__ gtw) {
  float vr[16], vi[16];
  // stage 0: span 256 (thread-private in-place: no mid-stage barrier)
  #pragma unroll
  for (int q = 0; q < 16; q++) { const int a = POS(tid + 256*q); vr[q] = sre[a]; vi[q] = sim[a]; }
  dft16<INV>(vr, vi);
  stage_twiddle<INV>(vr, vi, gtw[tid]);            // W_4096^tid
  #pragma unroll
  for (int q = 0; q < 16; q++) { const int a = POS(tid + 256*q); sre[a] = vr[q]; sim[a] = vi[q]; }
  __syncthreads();
  // stage 1: span 16
  const int base = (tid >> 4) * 256 + (tid & 15);
  #pragma unroll
  for (int q = 0; q < 16; q++) { const int a = POS(base + 16*q); vr[q] = sre[a]; vi[q] = sim[a]; }
  dft16<INV>(vr, vi);
  stage_twiddle<INV>(vr, vi, gtw[(tid & 15) << 4]); // W_256^(tid&15)
  #pragma unroll
  for (int q = 0; q < 16; q++) { const int a = POS(base + 16*q); sre[a] = vr[q]; sim[a] = vi[q]; }
  __syncthreads();
  // stage 2: span 1, scatter output to natural order (digit reversal)
  #pragma unroll
  for (int q = 0; q < 16; q++) { const int a = POS(16*tid + q); vr[q] = sre[a]; vi[q] = sim[a]; }
  dft16<INV>(vr, vi);
  __syncthreads();   // all reads done before scatter writes
  const int sg = 16*(tid & 15) + (tid >> 4);       // dr(16t+p) = 256p + sg
  #pragma unroll
  for (int p = 0; p < 16; p++) { const int a = POS(256*p + sg); sre[a] = vr[p]; sim[a] = vi[p]; }
  __syncthreads();
}

// ---- K0: diag extract, entropy zero, fp64-accurate twiddle tables ----
__global__ __launch_bounds__(256) void prep_kernel(
    const float* __restrict__ w1, float* __restrict__ diag,
    float2* __restrict__ gtw, float2* __restrict__ guntw, float* __restrict__ ent)
{
  int i = blockIdx.x * 256 + threadIdx.x;
  if (i < NF) {
    diag[i] = w1[(size_t)i * (NF + 1)];
  } else if (i < 2 * NF) {
    int f = i - NF;
    diag[i] = w1[(size_t)NF * NF + (size_t)f * (NF + 1)];
  } else if (i < 2 * NF + BATCH) {
    ent[i - 2 * NF] = 0.0f;
  } else if (i < 2 * NF + BATCH + 256) {
    int m = i - (2 * NF + BATCH);
    double a = -6.283185307179586 * (double)m / 4096.0;
    gtw[m] = make_float2((float)cos(a), (float)sin(a));
  } else if (i < 2 * NF + BATCH + 256 + NF) {
    int k = i - (2 * NF + BATCH + 256);
    double a = -6.283185307179586 * (double)k / 8192.0;
    guntw[k] = make_float2((float)cos(a), (float)sin(a));
  }
}

// ---- K1: [B][R][32] -> [B][32][R] tiled transpose ----
__global__ __launch_bounds__(256) void transpose_kernel(
    const float* __restrict__ src, float* __restrict__ dst, int R)
{
  __shared__ float tile[32][33];
  int tx = threadIdx.x & 31, ty = threadIdx.x >> 5;
  int r0 = blockIdx.x * 32;
  size_t b = blockIdx.y;
  const float* s = src + b * (size_t)R * 32;
  float* d = dst + b * (size_t)32 * R;
  #pragma unroll
  for (int i = 0; i < 4; i++) {
    int r = r0 + ty + 8 * i;
    if (r < R) tile[tx][ty + 8 * i] = s[(size_t)r * 32 + tx];
  }
  __syncthreads();
  #pragma unroll
  for (int i = 0; i < 4; i++) {
    int c = ty + 8 * i;
    int r = r0 + tx;
    if (r < R) d[(size_t)c * R + r] = tile[c][tx];
  }
}

// ---- K3: transpose back + x_var = x - x_inv ----
__global__ __launch_bounds__(256) void finalize_kernel(
    const float* __restrict__ xinv_t, const float* __restrict__ x,
    float* __restrict__ xvar, float* __restrict__ xinv)
{
  __shared__ float tile[32][33];
  int tx = threadIdx.x & 31, ty = threadIdx.x >> 5;
  int l0 = blockIdx.x * 32;
  size_t b = blockIdx.y;
  const float* s = xinv_t + b * (size_t)CH * LEN;
  #pragma unroll
  for (int i = 0; i < 4; i++) {
    int c = ty + 8 * i;
    tile[tx][c] = s[(size_t)c * LEN + l0 + tx];
  }
  __syncthreads();
  #pragma unroll
  for (int i = 0; i < 4; i++) {
    int l = l0 + ty + 8 * i;
    size_t idx = (b * LEN + l) * CH + tx;
    float v = tile[ty + 8 * i][tx];
    xinv[idx] = v;
    xvar[idx] = x[idx] - v;
  }
}

// ---- K2: per-(b,c): rfft -> logits -> gumbel softmax -> top-k -> irfft ----
__global__ __launch_bounds__(256, 4) void spectral_kernel(
    float* __restrict__ xt, const float* __restrict__ ut,
    const float* __restrict__ diag, const float* __restrict__ b1g,
    const float2* __restrict__ gtw, const float2* __restrict__ guntw,
    float* __restrict__ ent)
{
  __shared__ float sre[4360];         // POS(4096)=4352
  __shared__ float sim[4360];
  __shared__ unsigned hist[256];
  __shared__ float redbuf[8];
  __shared__ unsigned wsuf[4];
  __shared__ unsigned ubc[4];
  __shared__ float fbc[2];
  __shared__ int tielist[65];
  __shared__ int tkmax;

  const int tid = threadIdx.x;
  const int bc = blockIdx.x;
  float* xrow = xt + (size_t)bc * LEN;
  const float* urow = ut + (size_t)bc * NF;

  // ---- load x row (float4 = 2 complex per load) to natural LDS order
  #pragma unroll
  for (int i = 0; i < 8; i++) {
    const int m = tid + 256 * i;
    const float4 v = ((const float4*)xrow)[m];
    const int a0 = POS(2*m), a1 = POS(2*m + 1);
    sre[a0] = v.x; sim[a0] = v.y;
    sre[a1] = v.z; sim[a1] = v.w;
  }
  __syncthreads();

  // ---- forward 4096-pt FFT of z[n] = x[2n] + i x[2n+1]
  fft4096<false>(sre, sim, tid, gtw);

  // ---- untangle Z -> X (rfft bins 0..4096), natural order in LDS
  {
    float txr[17], txi[17];
    #pragma unroll
    for (int i = 0; i < 17; i++) {
      const int k = tid + 256 * i;
      if (k <= N2) {
        const int kk = k & (N2 - 1), km = (N2 - k) & (N2 - 1);
        const float a = sre[POS(kk)], b = sim[POS(kk)];
        const float c = sre[POS(km)], d = sim[POS(km)];
        const float xer = 0.5f * (a + c), xei = 0.5f * (b - d);
        const float xor_ = 0.5f * (b + d), xoi = 0.5f * (c - a);
        const float2 w = guntw[k];     // e^{-2pi i k/8192}
        txr[i] = xer + xor_ * w.x - xoi * w.y;
        txi[i] = xei + xor_ * w.y + xoi * w.x;
      }
    }
    __syncthreads();
    #pragma unroll
    for (int i = 0; i < 17; i++) {
      const int k = tid + 256 * i;
      if (k <= N2) { sre[POS(k)] = txr[i]; sim[POS(k)] = txi[i]; }
    }
    __syncthreads();
  }

  // ---- logits + gumbel -> z = (logit + g)/TAU
  float zloc[17];
  unsigned su[17];
  float lmax = -3.0e38f;
  #pragma unroll
  for (int i = 0; i < 17; i++) {
    const int k = tid + 256 * i;
    if (k <= N2) {
      const float re = sre[POS(k)], im = sim[POS(k)];
      const float d0 = diag[k], d1 = diag[NF + k];
      const float o_r = fmaxf(re * d0 - im * d1 + b1g[k], 0.0f);
      const float o_i = fmaxf(im * d0 + re * d1 + b1g[NF + k], 0.0f);
      const float logit = sqrtf(o_r * o_r + o_i * o_i);
      const float u = urow[k];
      const float g = -__logf(-__logf(u + 1e-10f) + 1e-10f);
      const float z = (logit + g) * 2.0f;   // 1/TAU
      zloc[i] = z;
      lmax = fmaxf(lmax, z);
    }
  }
  #pragma unroll
  for (int off = 32; off; off >>= 1) lmax = fmaxf(lmax, __shfl_xor(lmax, off, 64));
  if ((tid & 63) == 0) redbuf[tid >> 6] = lmax;
  __syncthreads();
  if (tid == 0) fbc[0] = fmaxf(fmaxf(redbuf[0], redbuf[1]), fmaxf(redbuf[2], redbuf[3]));
  __syncthreads();
  const float mx = fbc[0];

  float s1 = 0.0f, s2 = 0.0f;
  #pragma unroll
  for (int i = 0; i < 17; i++) {
    const int k = tid + 256 * i;
    if (k <= N2) {
      const float t = zloc[i] - mx;
      const float e = __expf(t);
      s1 += e; s2 += t * e;
      zloc[i] = e;                         // reuse as exp value
    }
  }
  #pragma unroll
  for (int off = 32; off; off >>= 1) { s1 += __shfl_xor(s1, off, 64); s2 += __shfl_xor(s2, off, 64); }
  if ((tid & 63) == 0) { redbuf[tid >> 6] = s1; redbuf[4 + (tid >> 6)] = s2; }
  __syncthreads();
  if (tid == 0) {
    const float S1a = redbuf[0] + redbuf[1] + redbuf[2] + redbuf[3];
    const float S2a = redbuf[4] + redbuf[5] + redbuf[6] + redbuf[7];
    fbc[1] = S1a;
    atomicAdd(&ent[bc >> 5], (__logf(S1a) - S2a / S1a) * (1.0f / CH));
  }
  __syncthreads();
  const float inv_s1 = 1.0f / fbc[1];
  #pragma unroll
  for (int i = 0; i < 17; i++) {
    const int k = tid + 256 * i;
    if (k <= N2) su[i] = sukey(zloc[i] * inv_s1);
  }

  // ---- radix-select the KSEL-th largest y_soft (4 x 8-bit passes)
  unsigned prefix = 0u, rank = KSEL;
  const int lane = tid & 63, wv = tid >> 6;
  for (int p = 24; p >= 0; p -= 8) {
    hist[tid] = 0u;
    __syncthreads();
    #pragma unroll
    for (int i = 0; i < 17; i++) {
      const int k = tid + 256 * i;
      if (k <= N2) {
        const unsigned s = su[i];
        if (((s >> p) >> 8) == ((prefix >> p) >> 8))
          atomicAdd(&hist[(s >> p) & 255u], 1u);
      }
    }
    __syncthreads();
    // parallel suffix scan over 256 bins (thread == bin)
    const unsigned h = hist[tid];
    unsigned sc = h;
    #pragma unroll
    for (int off = 1; off < 64; off <<= 1) {
      const unsigned o = __shfl_down(sc, off, 64);
      if (lane + off < 64) sc += o;
    }
    if (lane == 0) wsuf[wv] = sc;
    __syncthreads();
    unsigned add = 0;
    #pragma unroll
    for (int w2 = 0; w2 < 4; w2++) if (w2 > wv) add += wsuf[w2];
    const unsigned incl = sc + add;       // count of keys in bins >= tid
    const unsigned excl = incl - h;
    if (excl < rank && rank <= incl) {
      ubc[0] = prefix | ((unsigned)tid << p);
      ubc[1] = rank - excl;
    }
    __syncthreads();
    prefix = ubc[0]; rank = ubc[1];
  }
  const unsigned T = prefix;
  const unsigned need_eq = rank;

  // ---- stable tie handling: keep lowest-index equals
  if (tid == 0) ubc[2] = 0u;
  __syncthreads();
  #pragma unroll
  for (int i = 0; i < 17; i++) {
    const int k = tid + 256 * i;
    if (k <= N2 && su[i] == T) {
      const unsigned pos = atomicAdd(&ubc[2], 1u);
      if (pos < 64u) tielist[pos] = k;
    }
  }
  __syncthreads();
  if (tid == 0) {
    int n = (int)ubc[2]; if (n > 64) n = 64;
    for (int a = 1; a < n; a++) {
      const int key = tielist[a]; int j = a - 1;
      while (j >= 0 && tielist[j] > key) { tielist[j + 1] = tielist[j]; j--; }
      tielist[j + 1] = key;
    }
    tkmax = ((int)need_eq < n) ? tielist[need_eq] : 0x7fffffff;
  }
  __syncthreads();
  const int kmax = tkmax;

  // ---- hard mask: zero non-selected bins (threads own their k's)
  #pragma unroll
  for (int i = 0; i < 17; i++) {
    const int k = tid + 256 * i;
    if (k <= N2) {
      const bool keep = (su[i] > T) || (su[i] == T && k < kmax);
      if (!keep) { sre[POS(k)] = 0.0f; sim[POS(k)] = 0.0f; }
    }
  }
  __syncthreads();

  // ---- inverse untangle X -> Z'
  {
    float tzr[16], tzi[16];
    #pragma unroll
    for (int i = 0; i < 16; i++) {
      const int k = tid + 256 * i;
      const int km = N2 - k;
      const float a = sre[POS(k)], b = sim[POS(k)];
      const float c = sre[POS(km)], d = sim[POS(km)];
      const float xer = 0.5f * (a + c), xei = 0.5f * (b - d);
      const float tr = 0.5f * (a - c), ti = 0.5f * (b + d);
      const float2 w = guntw[k];
      const float cw = w.x, sw = -w.y;    // e^{+2pi i k/8192}
      const float xor_ = tr * cw - ti * sw, xoi = tr * sw + ti * cw;
      tzr[i] = xer - xoi;
      tzi[i] = xei + xor_;
    }
    __syncthreads();
    #pragma unroll
    for (int i = 0; i < 16; i++) {
      const int k = tid + 256 * i;
      sre[POS(k)] = tzr[i]; sim[POS(k)] = tzi[i];
    }
    __syncthreads();
  }

  // ---- inverse 4096-pt FFT (conj twiddles), natural in -> natural out
  fft4096<true>(sre, sim, tid, gtw);

  // ---- write x_inv row (float4), scale 1/4096
  const float scale = 1.0f / N2;
  #pragma unroll
  for (int i = 0; i < 8; i++) {
    const int m = tid + 256 * i;
    const int a0 = POS(2*m), a1 = POS(2*m + 1);
    float4 v;
    v.x = sre[a0] * scale; v.y = sim[a0] * scale;
    v.z = sre[a1] * scale; v.w = sim[a1] * scale;
    ((float4*)xrow)[m] = v;
  }
}

extern "C" void kernel_launch(void* const* d_in, const int* in_sizes, int n_in,
                              void* d_out, int out_size, void* d_ws, size_t ws_size,
                              hipStream_t stream) {
  (void)in_sizes; (void)n_in; (void)out_size; (void)ws_size;
  const float* x  = (const float*)d_in[0];
  const float* w1 = (const float*)d_in[1];
  const float* b1 = (const float*)d_in[2];
  const float* un = (const float*)d_in[3];
  float* xvar = (float*)d_out;
  float* xinv = xvar + (size_t)BATCH * LEN * CH;
  float* ent  = xinv + (size_t)BATCH * LEN * CH;

  float* xt    = (float*)d_ws;                       // [B*C][LEN], reused as x_inv_t
  float* ut    = xt + (size_t)BATCH * CH * LEN;      // [B*C][NF]
  float* diag  = ut + (size_t)BATCH * CH * NF;       // [2*NF]
  float2* gtw  = (float2*)(diag + 2 * NF);           // [256]
  float2* guntw= gtw + 256;                          // [NF]

  prep_kernel<<<51, 256, 0, stream>>>(w1, diag, gtw, guntw, ent);
  transpose_kernel<<<dim3(LEN / 32, BATCH), 256, 0, stream>>>(x, xt, LEN);
  transpose_kernel<<<dim3((NF + 31) / 32, BATCH), 256, 0, stream>>>(un, ut, NF);
  spectral_kernel<<<BATCH * CH, 256, 0, stream>>>(xt, ut, diag, b1, gtw, guntw, ent);
  finalize_kernel<<<dim3(LEN / 32, BATCH), 256, 0, stream>>>(xt, x, xvar, xinv);
}